// Round 1
// baseline (332.259 us; speedup 1.0000x reference)
//
#include <hip/hip_runtime.h>

// FilteredNoiseGenerator: B=32, t=4000, nbands=65, framesize=80, L_fir=129, L=208
// out[b, p] (p in [0,320000)) = sum over frames f, taps tau: x[b,f,m]*w[b,f,tau]
// with j = p+64, tau = j - 80f - m in [0,128].
//
// w[f][n] = hann[n] * zp[f][|n-64|],  zp[f][d] = (2*sum_k H[f][k]cos(2pi k d/129) - H[f][0])/129
// (zero_phase of a real half-spectrum is even; roll(nbands-1) centers it.)

#define NT 256
#define NFRM 32            // frames per workgroup (4000 % 32 == 0 -> 125 groups)
#define H_STRIDE 68        // 65 + zero pad, multiple of 4, == 4 mod 32
#define X_STRIDE 84        // 80 + pad, multiple of 4
#define W_STRIDE 164       // zero-padded w row: idx = W_P + tau, nonzero tau in [0,128]
#define W_P 16
#define OUT_LDS 2696       // 80*31 + 215 + 1

// conv chunk tiers sorted by descending MAC cost (chunk c covers d = 12c..12c+11)
__constant__ int ORD[18] = {7, 8, 9, 10, 6, 11, 5, 12, 4, 13, 3, 14, 2, 15, 1, 16, 0, 17};

__global__ void __launch_bounds__(NT)
fng_kernel(const float* __restrict__ Hg_, const float* __restrict__ Ng_,
           float* __restrict__ Og_) {
  __shared__ __align__(16) float sH[NFRM * H_STRIDE];
  __shared__ __align__(16) float sW[NFRM * W_STRIDE];
  __shared__ __align__(16) float sX[NFRM * X_STRIDE];
  __shared__ __align__(16) float sO[OUT_LDS];

  const int t  = threadIdx.x;
  const int bx = blockIdx.x;     // frame group 0..124
  const int b  = blockIdx.y;     // batch 0..31
  const int f0 = bx * NFRM;

  // ---------------- P0: zero LDS, stage H and x ----------------
  for (int i = t; i < NFRM * W_STRIDE; i += NT) sW[i] = 0.f;
  for (int i = t; i < OUT_LDS; i += NT) sO[i] = 0.f;
  {
    const float* Hg = Hg_ + ((size_t)(b * 4000 + f0)) * 65;
    for (int i = t; i < NFRM * H_STRIDE; i += NT) {
      int fi = i / H_STRIDE, kk = i - fi * H_STRIDE;
      sH[i] = (kk < 65) ? Hg[fi * 65 + kk] : 0.f;
    }
    const float* Ng = Ng_ + (size_t)b * 320000 + (size_t)f0 * 80;
    for (int i = t; i < NFRM * 80; i += NT) {
      int fi = i / 80, m = i - fi * 80;
      sX[fi * X_STRIDE + m] = Ng[i] * 2.f - 1.f;   // noise in [0,1) -> [-1,1)
    }
  }
  __syncthreads();

  // ------- P1: zp via Chebyshev cos recurrence, write windowed FIR -------
  // 288 tasks: (frame fi, d-block db of 8), d = 8*db + j, valid d <= 64
  for (int task = t; task < 288; task += NT) {
    const int fi = task & 31;
    const int db = task >> 5;
    const float TP129 = 6.28318530717958647692f / 129.f;
    float two_a[8], cc[8], cm[8], acc[8];
#pragma unroll
    for (int j = 0; j < 8; ++j) {
      float a = __cosf((float)(8 * db + j) * TP129);
      two_a[j] = 2.f * a; cc[j] = 1.f; cm[j] = a; acc[j] = 0.f;
      // k=0: cc = cos(0)=1, cm = cos(-theta)=a  -> next: 2a*1 - a = a = cos(theta)  OK
    }
    const float* hr = &sH[fi * H_STRIDE];
    const float h0 = hr[0];
    for (int k = 0; k < 68; k += 4) {          // k=65..67 are zero-padded
      float4 h4 = *(const float4*)&hr[k];
      const float hh[4] = {h4.x, h4.y, h4.z, h4.w};
#pragma unroll
      for (int mm = 0; mm < 4; ++mm) {
#pragma unroll
        for (int j = 0; j < 8; ++j) {
          acc[j] = fmaf(hh[mm], cc[j], acc[j]);
          float cn = fmaf(two_a[j], cc[j], -cm[j]);
          cm[j] = cc[j]; cc[j] = cn;
        }
      }
    }
    float* wr = &sW[fi * W_STRIDE];
#pragma unroll
    for (int j = 0; j < 8; ++j) {
      int d = 8 * db + j;
      if (d <= 64) {
        float zp = (2.f * acc[j] - h0) * (1.f / 129.f);
        float hp = 0.5f - 0.5f * __cosf((float)(64 + d) * TP129);
        wr[W_P + 64 + d] = hp * zp;
        if (d > 0) {
          float hm = 0.5f - 0.5f * __cosf((float)(64 - d) * TP129);
          wr[W_P + 64 - d] = hm * zp;
        }
      }
    }
  }
  __syncthreads();

  // ---------------- P2: convolution (scatter per frame into sO) ----------------
  // task q in [0,576): tier = q>>5 (cost-sorted chunk), fi = q&31.
  auto conv_task = [&](int q) {
    const int tier = q >> 5;
    const int fi = q & 31;
    const int c = ORD[tier];
    const int d0 = 12 * c;                       // 0..204
    const int mlo = max(0, d0 - 128);            // multiple of 4
    const int m0hi = min(76, d0 + 8);
    const int nstep = ((m0hi - mlo) >> 2) + 1;   // >= 1 for all chunks
    const float* wr = &sW[fi * W_STRIDE];
    const float* xr = &sX[fi * X_STRIDE];
    float acc[12];
#pragma unroll
    for (int i = 0; i < 12; ++i) acc[i] = 0.f;
    int m0 = mlo;
    const int base = W_P + d0 - mlo;
    float4 qa = *(const float4*)&wr[base - 4];
    float4 qb = *(const float4*)&wr[base];
    float4 qc = *(const float4*)&wr[base + 4];
    float4 qd = *(const float4*)&wr[base + 8];
#pragma unroll 4
    for (int s = 0; s < nstep; ++s) {
      float4 x4 = *(const float4*)&xr[m0];
      const float xv[4] = {x4.x, x4.y, x4.z, x4.w};
      const float w16[16] = {qa.x, qa.y, qa.z, qa.w, qb.x, qb.y, qb.z, qb.w,
                             qc.x, qc.y, qc.z, qc.w, qd.x, qd.y, qd.z, qd.w};
#pragma unroll
      for (int mm = 0; mm < 4; ++mm)
#pragma unroll
        for (int i = 0; i < 12; ++i)
          acc[i] = fmaf(xv[mm], w16[4 + i - mm], acc[i]);  // rel in [1,15]
      m0 += 4;
      qd = qc; qc = qb; qb = qa;
      qa = *(const float4*)&wr[W_P + d0 - m0 - 4];  // >= 0 for all chunks (checked)
    }
    float* ob = &sO[80 * fi + d0];
#pragma unroll
    for (int i = 0; i < 12; ++i)
      atomicAdd(&ob[i], acc[i]);   // ds_add; d>207 entries are exact zeros
  };
  conv_task(t);
  conv_task(511 - t);
  if (t < 64) conv_task(512 + t);
  __syncthreads();

  // ---------------- P3: writeout (trim 64, overlap via atomics) ----------------
  {
    float* Ob = Og_ + (size_t)b * 320000;
    const int jb = 2560 * bx - 64;   // p = jb + u
    for (int u = t; u < 2688; u += NT) {
      int p = jb + u;
      if (p >= 0 && p < 320000) {
        float v = sO[u];
        if (u < 128 || u >= 2560) atomicAdd(&Ob[p], v);  // overlap with neighbor wg
        else Ob[p] = v;                                   // single writer
      }
    }
  }
}

extern "C" void kernel_launch(void* const* d_in, const int* in_sizes, int n_in,
                              void* d_out, int out_size, void* d_ws, size_t ws_size,
                              hipStream_t stream) {
  const float* H     = (const float*)d_in[0];   // [32,4000,65] fp32
  const float* noise = (const float*)d_in[1];   // [32,4000,80] fp32
  float* out = (float*)d_out;                   // [32,320000] fp32
  (void)in_sizes; (void)n_in; (void)d_ws; (void)ws_size;

  hipMemsetAsync(d_out, 0, (size_t)out_size * sizeof(float), stream);
  dim3 grid(125, 32, 1);
  fng_kernel<<<grid, NT, 0, stream>>>(H, noise, out);
}